// Round 3
// baseline (1025.364 us; speedup 1.0000x reference)
//
#include <hip/hip_runtime.h>
#include <hip/hip_bf16.h>
#include <stdint.h>
#include <type_traits>

typedef __attribute__((ext_vector_type(8))) short bf16x8;
typedef __attribute__((ext_vector_type(4))) float f32x4;
typedef __attribute__((ext_vector_type(4))) int i32x4;

struct Scalars {
  double sum_wk;            // sum |Wk|
  double sum_wo;            // sum |Wo|
  unsigned int max_x_bits;  // max|x| as uint bits (nonneg float)
  unsigned int max_y_bits;  // max|x+retrieved| as uint bits
};

__device__ __forceinline__ unsigned short f2bf(float f) {
  __hip_bfloat16 h = __float2bfloat16(f);
  return *reinterpret_cast<unsigned short*>(&h);
}

// async global->LDS, 16B per lane; LDS dest is wave-uniform base + lane*16
__device__ __forceinline__ void async16(void* lds, const void* g) {
  __builtin_amdgcn_global_load_lds((__attribute__((address_space(1))) void*)g,
                                   (__attribute__((address_space(3))) void*)lds, 16, 0, 0);
}

// MFMA overloads: bf16 (K=32) and i8 (K=64), both 16B operands.
__device__ __forceinline__ f32x4 mm(bf16x8 a, bf16x8 b, f32x4 c) {
  return __builtin_amdgcn_mfma_f32_16x16x32_bf16(a, b, c, 0, 0, 0);
}
__device__ __forceinline__ i32x4 mm(i32x4 a, i32x4 b, i32x4 c) {
  return __builtin_amdgcn_mfma_i32_16x16x64_i8(a, b, c, 0, 0, 0);
}

// ---------------- reductions ----------------
__global__ __launch_bounds__(256) void abssum2_kernel(const float* __restrict__ wa,
                                                      const float* __restrict__ wb,
                                                      double* __restrict__ out) {
  const float* w = blockIdx.y ? wb : wa;
  const size_t n = 1048576;
  size_t tid = (size_t)blockIdx.x * blockDim.x + threadIdx.x;
  size_t stride = (size_t)gridDim.x * blockDim.x;
  double s = 0.0;
  for (size_t i = tid * 4; i < n; i += stride * 4) {
    float4 v = *(const float4*)(w + i);
    s += (double)fabsf(v.x) + (double)fabsf(v.y) + (double)fabsf(v.z) + (double)fabsf(v.w);
  }
#pragma unroll
  for (int o = 32; o > 0; o >>= 1) s += __shfl_xor(s, o);
  __shared__ double sm[4];
  if ((threadIdx.x & 63) == 0) sm[threadIdx.x >> 6] = s;
  __syncthreads();
  if (threadIdx.x == 0) atomicAdd(&out[blockIdx.y], sm[0] + sm[1] + sm[2] + sm[3]);
}

__global__ __launch_bounds__(256) void absmax_kernel(const float* __restrict__ x, size_t n,
                                                     unsigned int* __restrict__ out) {
  size_t tid = (size_t)blockIdx.x * blockDim.x + threadIdx.x;
  size_t stride = (size_t)gridDim.x * blockDim.x;
  float m = 0.0f;
  for (size_t i = tid * 4; i < n; i += stride * 4) {
    float4 v = *(const float4*)(x + i);
    m = fmaxf(m, fmaxf(fmaxf(fabsf(v.x), fabsf(v.y)), fmaxf(fabsf(v.z), fabsf(v.w))));
  }
#pragma unroll
  for (int o = 32; o > 0; o >>= 1) m = fmaxf(m, __shfl_xor(m, o));
  __shared__ float sm[4];
  if ((threadIdx.x & 63) == 0) sm[threadIdx.x >> 6] = m;
  __syncthreads();
  if (threadIdx.x == 0)
    atomicMax(out, __float_as_uint(fmaxf(fmaxf(sm[0], sm[1]), fmaxf(sm[2], sm[3]))));
}

// ---------------- quantize / cast (int8 paths) ----------------
__global__ __launch_bounds__(256) void quant_act_i8_kernel(const float* __restrict__ x,
                                                           char* __restrict__ q,
                                                           const unsigned int* __restrict__ maxbits,
                                                           size_t n) {
  const float isc = __uint_as_float(*maxbits) / 127.0f;  // matches np: max/127.0 fp32
  size_t tid = (size_t)blockIdx.x * blockDim.x + threadIdx.x;
  size_t stride = (size_t)gridDim.x * blockDim.x;
  for (size_t i = tid * 4; i < n; i += stride * 4) {
    float4 v = *(const float4*)(x + i);
    char4 o;
    o.x = (char)(int)fminf(fmaxf(rintf(v.x / isc), -128.f), 127.f);
    o.y = (char)(int)fminf(fmaxf(rintf(v.y / isc), -128.f), 127.f);
    o.z = (char)(int)fminf(fmaxf(rintf(v.z / isc), -128.f), 127.f);
    o.w = (char)(int)fminf(fmaxf(rintf(v.w / isc), -128.f), 127.f);
    *(char4*)(q + i) = o;
  }
}

__global__ __launch_bounds__(256) void quant_w2_kernel(const float* __restrict__ Wk,
                                                       const float* __restrict__ Wo,
                                                       char* __restrict__ qk8,
                                                       char* __restrict__ qo8,
                                                       const double* __restrict__ sums) {
  const float* W = blockIdx.y ? Wo : Wk;
  char* q = blockIdx.y ? qo8 : qk8;
  const size_t n = 1048576;
  const float wsc = (float)(sums[blockIdx.y] * (1.0 / 1048576.0));
  const float thr = 0.5f * wsc;
  size_t tid = (size_t)blockIdx.x * blockDim.x + threadIdx.x;
  size_t stride = (size_t)gridDim.x * blockDim.x;
  for (size_t i = tid * 4; i < n; i += stride * 4) {
    float4 v = *(const float4*)(W + i);
    char4 o;
    o.x = (char)(fabsf(v.x) > thr ? (v.x > 0.f ? 1 : -1) : 0);
    o.y = (char)(fabsf(v.y) > thr ? (v.y > 0.f ? 1 : -1) : 0);
    o.z = (char)(fabsf(v.z) > thr ? (v.z > 0.f ? 1 : -1) : 0);
    o.w = (char)(fabsf(v.w) > thr ? (v.w > 0.f ? 1 : -1) : 0);
    *(char4*)(q + i) = o;
  }
}

__global__ __launch_bounds__(256) void cast_bf16_kernel(const float* __restrict__ src,
                                                        __hip_bfloat16* __restrict__ dst,
                                                        size_t n) {
  size_t tid = (size_t)blockIdx.x * blockDim.x + threadIdx.x;
  size_t stride = (size_t)gridDim.x * blockDim.x;
  for (size_t i = tid * 4; i < n; i += stride * 4) {
    float4 v = *(const float4*)(src + i);
    ushort4 o;
    o.x = f2bf(v.x); o.y = f2bf(v.y); o.z = f2bf(v.z); o.w = f2bf(v.w);
    *(ushort4*)((unsigned short*)dst + i) = o;
  }
}

// memory_values [2048][1024] f32 -> mvT [1024][2048] bf16
__global__ void transpose_mv_kernel(const float* __restrict__ mv,
                                    __hip_bfloat16* __restrict__ mvT) {
  __shared__ float tile[32][33];
  int tx = threadIdx.x, ty = threadIdx.y;
  int e = blockIdx.x * 32 + tx;
  int m = blockIdx.y * 32 + ty;
  tile[ty][tx] = mv[(size_t)m * 1024 + e];
  __syncthreads();
  int om = blockIdx.y * 32 + tx;
  mvT[(size_t)(blockIdx.x * 32 + ty) * 2048 + om] = __float2bfloat16(tile[tx][ty]);
}

// ---------------- softmax over rows of 2048, in-place bf16 ----------------
__global__ __launch_bounds__(256) void softmax_kernel(__hip_bfloat16* __restrict__ sims) {
  unsigned short* row = (unsigned short*)(sims + (size_t)blockIdx.x * 2048);
  const int t = threadIdx.x;
  const int l = t & 63, wv = t >> 6;
  uint4 r4 = *(const uint4*)(row + t * 8);
  float v[8];
  v[0] = __uint_as_float(r4.x << 16); v[1] = __uint_as_float(r4.x & 0xffff0000u);
  v[2] = __uint_as_float(r4.y << 16); v[3] = __uint_as_float(r4.y & 0xffff0000u);
  v[4] = __uint_as_float(r4.z << 16); v[5] = __uint_as_float(r4.z & 0xffff0000u);
  v[6] = __uint_as_float(r4.w << 16); v[7] = __uint_as_float(r4.w & 0xffff0000u);
  float m = v[0];
#pragma unroll
  for (int i = 1; i < 8; ++i) m = fmaxf(m, v[i]);
#pragma unroll
  for (int o = 32; o > 0; o >>= 1) m = fmaxf(m, __shfl_xor(m, o));
  __shared__ float red[4], red2[4];
  if (l == 0) red[wv] = m;
  __syncthreads();
  m = fmaxf(fmaxf(red[0], red[1]), fmaxf(red[2], red[3]));
  float s = 0.f;
#pragma unroll
  for (int i = 0; i < 8; ++i) { v[i] = expf(v[i] - m); s += v[i]; }
#pragma unroll
  for (int o = 32; o > 0; o >>= 1) s += __shfl_xor(s, o);
  if (l == 0) red2[wv] = s;
  __syncthreads();
  s = red2[0] + red2[1] + red2[2] + red2[3];
  unsigned short b[8];
#pragma unroll
  for (int i = 0; i < 8; ++i) b[i] = f2bf(v[i] / s);
  uint4 o4;
  o4.x = (unsigned)b[0] | ((unsigned)b[1] << 16);
  o4.y = (unsigned)b[2] | ((unsigned)b[3] << 16);
  o4.z = (unsigned)b[4] | ((unsigned)b[5] << 16);
  o4.w = (unsigned)b[6] | ((unsigned)b[7] << 16);
  *(uint4*)(row + t * 8) = o4;
}

// ---------- persistent 256x256 NT MFMA GEMM, 4-barrier phases, counted vmcnt ----
// C[m,n] = sum_k A[m,k]*B[n,k], 128-byte K-tiles (bf16 BK=64 / i8 BK=128).
// Grid = 256 blocks (1/CU), each block owns TPB consecutive column tiles of one
// 256-row panel (A reused TPB x from L2). Staging pipeline is CONTINUOUS across
// output tiles (kt indexes K-tiles globally; only the final 2 TSTEPs drain).
// 512 threads = 8 waves (2M x 4N); per-wave output 128x64.
// LDS [A0,A1,B0,B1][slot][16KiB], rows XOR-swizzled in 16B chunks (pre-swizzled
// global_load_lds source, same XOR on ds_read).
// Per K-tile: 4 phases {STG issue; MFMA quadrant; barrier}; one WVM(6)+barrier
// at p4 retires exactly tile kt+1, after which kt+1's frags are ds_read.
// All lgkm waits are compiler-managed (graduated, dataflow-driven): ds_reads are
// plain loads, no manual drains, no order pins except at barriers.
// EPI: 1=bf16(acc/32)  2=f32(acc+aux)+absmax  3=bf16(acc*sK+aux[col])
// 4=f32(acc*sO+aux[col]).
#define BAR8() { __builtin_amdgcn_sched_barrier(0); asm volatile("" ::: "memory"); \
                 __builtin_amdgcn_s_barrier(); asm volatile("" ::: "memory"); }
#define WVM(N) asm volatile("s_waitcnt vmcnt(" #N ")" ::: "memory")

template <int EPI, int NTS, int TPB>
__global__ __launch_bounds__(512, 2) void gemm8p(
    const char* __restrict__ A, const char* __restrict__ B, void* __restrict__ C,
    const float* __restrict__ aux, Scalars* __restrict__ sc, int Ndim) {
  constexpr bool I8 = (EPI >= 3);
  using FR  = typename std::conditional<I8, i32x4, bf16x8>::type;
  using ACC = typename std::conditional<I8, i32x4, f32x4>::type;
  constexpr int NT = 1 << NTS;        // K-tiles per output tile
  constexpr int KTOT = NT * TPB;      // K-tiles per block (global kt range)
  constexpr int KB = 128 << NTS;      // bytes per A/B row
  __shared__ __align__(16) char lds[4][2][16384];  // [A0,A1,B0,B1][slot][16KiB]

  // XCD-contiguous linear id; 2 block-groups per 256-row panel.
  const int lin = ((blockIdx.x & 7) << 5) + (blockIdx.x >> 3);
  const int by = lin >> 1;
  const int bx0 = (lin & 1) * TPB;
  const int rowBlk = by * 256;
  const int colBlk0 = bx0 * 256;

  const int t = threadIdx.x, w = t >> 6, l = t & 63;
  const int wm = w >> 2, wn = w & 3;
  const int quad = l >> 4, m16 = l & 15;

  // per-thread staging byte-offsets (K- and tile-invariant parts)
  int voA[2][2], voB[2][2];
#pragma unroll
  for (int hf = 0; hf < 2; ++hf)
#pragma unroll
    for (int j = 0; j < 2; ++j) {
      const int idx = j * 64 + (t >> 3);
      const int kby = ((t & 7) ^ (idx & 7)) << 4;
      voA[hf][j] = (rowBlk + ((idx >> 6) << 7) + (hf << 6) + (idx & 63)) * KB + kby;
      voB[hf][j] = (((idx >> 5) << 6) + (hf << 5) + (idx & 31)) * KB + kby;
    }

  // ds_read base pointers; fragment reads are base + compile-time offset.
  const char* baA[2];
  const char* baB[2];
#pragma unroll
  for (int ks = 0; ks < 2; ++ks) {
    const int x16 = ((ks << 6) + (quad << 4)) ^ ((m16 & 7) << 4);
    baA[ks] = &lds[0][0][(wm * 64 + m16) * 128 + x16];
    baB[ks] = &lds[2][0][(wn * 32 + m16) * 128 + x16];
  }

#define STG_A(slot, hf, kt)                                                         \
  if ((kt) < KTOT) {                                                                \
    const char* gp = A + (((kt) & (NT - 1)) << 7);                                  \
    _Pragma("unroll") for (int j = 0; j < 2; ++j)                                   \
      async16(&lds[hf][slot][j * 8192 + (w << 10)], gp + voA[hf][j]);               \
  }
#define STG_B(slot, hf, kt)                                                         \
  if ((kt) < KTOT) {                                                                \
    const char* gp = B + (size_t)(colBlk0 + (((kt) >> NTS) << 8)) * KB +            \
                     (((kt) & (NT - 1)) << 7);                                      \
    _Pragma("unroll") for (int j = 0; j < 2; ++j)                                   \
      async16(&lds[2 + (hf)][slot][j * 8192 + (w << 10)], gp + voB[hf][j]);         \
  }

#define LD_A(dst, slot, hf, f, ks) \
  dst = *(const FR*)(baA[ks] + ((hf)*32768 + (slot)*16384 + (f)*2048));
#define LD_B(dst, slot, hf, gg, ks) \
  dst = *(const FR*)(baB[ks] + ((hf)*32768 + (slot)*16384 + (gg)*2048));

#define R_A0(s) { _Pragma("unroll") for (int f_ = 0; f_ < 4; ++f_) { LD_A(af[f_][0], s, 0, f_, 0); LD_A(af[f_][1], s, 0, f_, 1); } }
#define R_A1(s) { _Pragma("unroll") for (int f_ = 0; f_ < 4; ++f_) { LD_A(af[f_][0], s, 1, f_, 0); LD_A(af[f_][1], s, 1, f_, 1); } }
#define R_B0(s) { _Pragma("unroll") for (int g_ = 0; g_ < 2; ++g_) { LD_B(b0[g_][0], s, 0, g_, 0); LD_B(b0[g_][1], s, 0, g_, 1); } }
#define R_B1(s) { _Pragma("unroll") for (int g_ = 0; g_ < 2; ++g_) { LD_B(b1[g_][0], s, 1, g_, 0); LD_B(b1[g_][1], s, 1, g_, 1); } }

#define MM8(FO, GO, BR)                                                             \
  __builtin_amdgcn_s_setprio(1);                                                    \
  _Pragma("unroll") for (int f_ = 0; f_ < 4; ++f_)                                  \
    _Pragma("unroll") for (int g_ = 0; g_ < 2; ++g_) {                              \
      acc[(FO) + f_][(GO) + g_] = mm(af[f_][0], BR[g_][0], acc[(FO) + f_][(GO) + g_]); \
      acc[(FO) + f_][(GO) + g_] = mm(af[f_][1], BR[g_][1], acc[(FO) + f_][(GO) + g_]); \
    }                                                                               \
  __builtin_amdgcn_s_setprio(0);

// Per-tile step, 4 barriers. Entering p1: this tile's A0,B0,B1 reads in flight
// (issued at previous p4-end); af holds A0 after compiler's graduated waits.
#define TSTEP(s, kt, last)                                                          \
  {                                                                                 \
    /* p1 (mh0,nh0) */                                                              \
    STG_A((s) ^ 1, 1, (kt) + 1);                                                    \
    MM8(0, 0, b0);                                                                  \
    BAR8();                                                                         \
    /* p2 (mh0,nh1); A1 reads after last af use (WAR by dataflow) */                \
    STG_A(s, 0, (kt) + 2);                                                          \
    MM8(0, 2, b1);                                                                  \
    R_A1(s);                                                                        \
    BAR8();                                                                         \
    /* p3 (mh1,nh0) */                                                              \
    STG_B(s, 0, (kt) + 2);                                                          \
    MM8(4, 0, b0);                                                                  \
    BAR8();                                                                         \
    /* p4 (mh1,nh1); WVM retires tile kt+1, then its frags are read */              \
    STG_B(s, 1, (kt) + 2);                                                          \
    if (last) { WVM(0); } else { WVM(6); }                                          \
    BAR8();                                                                         \
    MM8(4, 2, b1);                                                                  \
    R_A0((s) ^ 1); R_B0((s) ^ 1); R_B1((s) ^ 1);                                    \
  }

  FR af[4][2], b0[2][2], b1[2][2];
  ACC acc[8][4] = {};

  float sK = 0.0f;
  if constexpr (EPI == 3)
    sK = (float)(sc->sum_wk * (1.0 / 1048576.0)) * (__uint_as_float(sc->max_x_bits) / 127.0f);
  if constexpr (EPI == 4)
    sK = (float)(sc->sum_wo * (1.0 / 1048576.0)) * (__uint_as_float(sc->max_y_bits) / 127.0f);

  // Prologue: tiles 0 (A0,B0,B1,A1) + 1 (A0,B0,B1); WVM(6) retires exactly
  // tile 0's 8 loads; then tile 0's fragments are read.
  STG_A(0, 0, 0); STG_B(0, 0, 0); STG_B(0, 1, 0); STG_A(0, 1, 0);
  STG_A(1, 0, 1); STG_B(1, 0, 1); STG_B(1, 1, 1);
  WVM(6);
  BAR8();
  R_A0(0); R_B0(0); R_B1(0);

  for (int tile = 0; tile < TPB; ++tile) {
    for (int it = 0; it < NT / 2; ++it) {
      const int kt = tile * NT + it * 2;
      TSTEP(0, kt, (kt) >= KTOT - 2);
      TSTEP(1, kt + 1, (kt + 1) >= KTOT - 2);
    }

    // ---------------- per-tile epilogue (no LDS, no sync) ----------------
    const int colBlk = (bx0 + tile) * 256;
    float amax = 0.0f;
#pragma unroll
    for (int f = 0; f < 8; ++f) {
#pragma unroll
      for (int g = 0; g < 4; ++g) {
        const int col = colBlk + wn * 64 + g * 16 + m16;
#pragma unroll
        for (int rg = 0; rg < 4; ++rg) {
          const int row = rowBlk + wm * 128 + f * 16 + quad * 4 + rg;
          if constexpr (EPI == 1) {
            ((__hip_bfloat16*)C)[(size_t)row * Ndim + col] =
                __float2bfloat16(acc[f][g][rg] * 0.03125f);
          } else if constexpr (EPI == 2) {
            float v = acc[f][g][rg] + aux[(size_t)row * Ndim + col];
            ((float*)C)[(size_t)row * Ndim + col] = v;
            amax = fmaxf(amax, fabsf(v));
          } else if constexpr (EPI == 3) {
            ((__hip_bfloat16*)C)[(size_t)row * Ndim + col] =
                __float2bfloat16((float)acc[f][g][rg] * sK + aux[col]);
          } else {
            ((float*)C)[(size_t)row * Ndim + col] = (float)acc[f][g][rg] * sK + aux[col];
          }
        }
      }
    }
    if constexpr (EPI == 2) {
#pragma unroll
      for (int o = 32; o > 0; o >>= 1) amax = fmaxf(amax, __shfl_xor(amax, o));
      if (l == 0) atomicMax(&sc->max_y_bits, __float_as_uint(amax));
    }
    // reset accumulators for next output tile
#pragma unroll
    for (int f = 0; f < 8; ++f)
#pragma unroll
      for (int g = 0; g < 4; ++g) acc[f][g] = ACC{0, 0, 0, 0};
  }
#undef STG_A
#undef STG_B
#undef LD_A
#undef LD_B
#undef R_A0
#undef R_A1
#undef R_B0
#undef R_B1
#undef MM8
#undef TSTEP
}

extern "C" void kernel_launch(void* const* d_in, const int* in_sizes, int n_in,
                              void* d_out, int out_size, void* d_ws, size_t ws_size,
                              hipStream_t stream) {
  (void)in_sizes; (void)n_in; (void)out_size; (void)ws_size;
  const float* x  = (const float*)d_in[0];   // [8,4096,1024]
  const float* mk = (const float*)d_in[1];   // [2048,1024]
  const float* mv = (const float*)d_in[2];   // [2048,1024]
  const float* Wk = (const float*)d_in[3];   // [1024,1024]
  const float* bk = (const float*)d_in[4];   // [1024]
  // d_in[5], d_in[6] = Wv, bv -> dead w.r.t. output; skipped.
  const float* Wo = (const float*)d_in[7];
  const float* bo = (const float*)d_in[8];
  float* out = (float*)d_out;

  const int M = 32768, E = 1024, MEM = 2048;

  char* ws = (char*)d_ws;
  Scalars* sc = (Scalars*)ws;
  const size_t off0 = 256;
  char* qx8 = ws + off0;                                            // 32 MB
  __hip_bfloat16* qk = (__hip_bfloat16*)(ws + off0 + (size_t)M * E); // 64 MB
  float* y = (float*)(ws + off0);                                   // reuses qx8+qk region (128 MB)
  const size_t off1 = off0 + (size_t)M * E * 4;
  __hip_bfloat16* sims = (__hip_bfloat16*)(ws + off1);              // 128 MB
  char* qy8 = (char*)sims;                                          // reuses sims (32 MB)
  const size_t off2 = off1 + (size_t)M * MEM * 2;
  char* qWk8 = ws + off2;                                           // 1 MB
  char* qWo8 = qWk8 + (size_t)E * E;                                // 1 MB
  __hip_bfloat16* mkb = (__hip_bfloat16*)(qWo8 + (size_t)E * E);    // 4 MB
  __hip_bfloat16* mvT = mkb + (size_t)MEM * E;                      // 4 MB

  hipMemsetAsync(ws, 0, 256, stream);

  abssum2_kernel<<<dim3(256, 2), dim3(256), 0, stream>>>(Wk, Wo, &sc->sum_wk);
  absmax_kernel<<<dim3(2048), dim3(256), 0, stream>>>(x, (size_t)M * E, &sc->max_x_bits);

  quant_act_i8_kernel<<<dim3(2048), dim3(256), 0, stream>>>(x, qx8, &sc->max_x_bits, (size_t)M * E);
  quant_w2_kernel<<<dim3(256, 2), dim3(256), 0, stream>>>(Wk, Wo, qWk8, qWo8, &sc->sum_wk);
  cast_bf16_kernel<<<dim3(256), dim3(256), 0, stream>>>(mk, mkb, (size_t)MEM * E);
  transpose_mv_kernel<<<dim3(E / 32, MEM / 32), dim3(32, 32), 0, stream>>>(mv, mvT);

  // qk = bf16((qx @ qWk^T) * s_k + bk)      [i8, KB=1024, NT=8, TPB=2]
  gemm8p<3, 3, 2><<<dim3(256), dim3(512), 0, stream>>>(qx8, qWk8, qk, bk, sc, E);
  // sims = bf16((qk @ mk^T) / 32)           [bf16, KB=2048, NT=16, TPB=4]
  gemm8p<1, 4, 4><<<dim3(256), dim3(512), 0, stream>>>(
      (const char*)qk, (const char*)mkb, sims, nullptr, sc, MEM);
  // softmax rows (in place)
  softmax_kernel<<<dim3(M), dim3(256), 0, stream>>>(sims);
  // y = probs @ mv + x   (+ global max|y|)   [bf16, KB=4096, NT=32, TPB=2]
  gemm8p<2, 5, 2><<<dim3(256), dim3(512), 0, stream>>>(
      (const char*)sims, (const char*)mvT, y, x, sc, E);
  // qy = quant(y)
  quant_act_i8_kernel<<<dim3(2048), dim3(256), 0, stream>>>(y, qy8, &sc->max_y_bits, (size_t)M * E);
  // out = (qy @ qWo^T) * s_o + bo           [i8, KB=1024, NT=8, TPB=2]
  gemm8p<4, 3, 2><<<dim3(256), dim3(512), 0, stream>>>(qy8, qWo8, out, bo, sc, E);
}

// Round 4
// 738.043 us; speedup vs baseline: 1.3893x; 1.3893x over previous
//
#include <hip/hip_runtime.h>
#include <hip/hip_bf16.h>
#include <stdint.h>
#include <type_traits>

typedef __attribute__((ext_vector_type(8))) short bf16x8;
typedef __attribute__((ext_vector_type(4))) int i32x4;
typedef __attribute__((ext_vector_type(16))) float f32x16;
typedef __attribute__((ext_vector_type(16))) int i32x16;

struct Scalars {
  double sum_wk;            // sum |Wk|
  double sum_wo;            // sum |Wo|
  unsigned int max_x_bits;  // max|x| as uint bits (nonneg float)
  unsigned int max_y_bits;  // max|x+retrieved| as uint bits
};

__device__ __forceinline__ unsigned short f2bf(float f) {
  __hip_bfloat16 h = __float2bfloat16(f);
  return *reinterpret_cast<unsigned short*>(&h);
}

// async global->LDS, 16B per lane; LDS dest is wave-uniform base + lane*16
__device__ __forceinline__ void async16(void* lds, const void* g) {
  __builtin_amdgcn_global_load_lds((__attribute__((address_space(1))) void*)g,
                                   (__attribute__((address_space(3))) void*)lds, 16, 0, 0);
}

// XCD-aware tile swizzle: consecutive blockIdx go round-robin to XCDs (bid%8);
// give each XCD a contiguous run of row-strips, col-blocks innermost.
__device__ __forceinline__ void tile_swizzle(int nxShift, int& bx, int& by) {
  const int per = gridDim.x >> 3;
  const int tile = (blockIdx.x & 7) * per + (blockIdx.x >> 3);
  bx = tile & ((1 << nxShift) - 1);
  by = tile >> nxShift;
}

// MFMA overloads: bf16 32x32x16 and i8 32x32x32, both 16B operands, 16-reg acc.
__device__ __forceinline__ f32x16 mm32(bf16x8 a, bf16x8 b, f32x16 c) {
  return __builtin_amdgcn_mfma_f32_32x32x16_bf16(a, b, c, 0, 0, 0);
}
__device__ __forceinline__ i32x16 mm32(i32x4 a, i32x4 b, i32x16 c) {
  return __builtin_amdgcn_mfma_i32_32x32x32_i8(a, b, c, 0, 0, 0);
}

// ---------------- stats: y=0 abssum(Wk), y=1 abssum(Wo), y=2 absmax(x) ----------
__global__ __launch_bounds__(256) void stats_kernel(const float* __restrict__ Wk,
                                                    const float* __restrict__ Wo,
                                                    const float* __restrict__ x,
                                                    Scalars* __restrict__ sc) {
  const int which = blockIdx.y;
  size_t tid = (size_t)blockIdx.x * 256 + threadIdx.x;
  size_t stride = (size_t)gridDim.x * 256;
  if (which < 2) {
    const float* w = which ? Wo : Wk;
    const size_t n = 1048576;
    double s = 0.0;
    for (size_t i = tid * 4; i < n; i += stride * 4) {
      float4 v = *(const float4*)(w + i);
      s += (double)fabsf(v.x) + (double)fabsf(v.y) + (double)fabsf(v.z) + (double)fabsf(v.w);
    }
#pragma unroll
    for (int o = 32; o > 0; o >>= 1) s += __shfl_xor(s, o);
    __shared__ double sm[4];
    if ((threadIdx.x & 63) == 0) sm[threadIdx.x >> 6] = s;
    __syncthreads();
    if (threadIdx.x == 0)
      atomicAdd(which ? &sc->sum_wo : &sc->sum_wk, sm[0] + sm[1] + sm[2] + sm[3]);
  } else {
    const size_t n = (size_t)32768 * 1024;
    float m = 0.0f;
    for (size_t i = tid * 4; i < n; i += stride * 4) {
      float4 v = *(const float4*)(x + i);
      m = fmaxf(m, fmaxf(fmaxf(fabsf(v.x), fabsf(v.y)), fmaxf(fabsf(v.z), fabsf(v.w))));
    }
#pragma unroll
    for (int o = 32; o > 0; o >>= 1) m = fmaxf(m, __shfl_xor(m, o));
    __shared__ float smf[4];
    if ((threadIdx.x & 63) == 0) smf[threadIdx.x >> 6] = m;
    __syncthreads();
    if (threadIdx.x == 0)
      atomicMax(&sc->max_x_bits,
                __float_as_uint(fmaxf(fmaxf(smf[0], smf[1]), fmaxf(smf[2], smf[3]))));
  }
}

// ---------------- prep: y=0 quantW(Wk), y=1 quantW(Wo), y=2 cast(mk),
//                  y=3 transpose(mv), y=4 quantAct(x) -------------------------
__global__ __launch_bounds__(256) void prep_kernel(
    const float* __restrict__ Wk, const float* __restrict__ Wo,
    const float* __restrict__ mk, const float* __restrict__ mv,
    const float* __restrict__ x, char* __restrict__ qWk8, char* __restrict__ qWo8,
    __hip_bfloat16* __restrict__ mkb, __hip_bfloat16* __restrict__ mvT,
    char* __restrict__ qx8, const Scalars* __restrict__ sc) {
  __shared__ float tl[32][33];
  const int which = blockIdx.y;
  const int t = threadIdx.x;
  size_t tid = (size_t)blockIdx.x * 256 + t;
  size_t stride = (size_t)gridDim.x * 256;
  if (which < 2) {
    const float* W = which ? Wo : Wk;
    char* q = which ? qWo8 : qWk8;
    const double sum = which ? sc->sum_wo : sc->sum_wk;
    const float thr = 0.5f * (float)(sum * (1.0 / 1048576.0));
    const size_t n = 1048576;
    for (size_t i = tid * 4; i < n; i += stride * 4) {
      float4 v = *(const float4*)(W + i);
      char4 o;
      o.x = (char)(fabsf(v.x) > thr ? (v.x > 0.f ? 1 : -1) : 0);
      o.y = (char)(fabsf(v.y) > thr ? (v.y > 0.f ? 1 : -1) : 0);
      o.z = (char)(fabsf(v.z) > thr ? (v.z > 0.f ? 1 : -1) : 0);
      o.w = (char)(fabsf(v.w) > thr ? (v.w > 0.f ? 1 : -1) : 0);
      *(char4*)(q + i) = o;
    }
  } else if (which == 2) {
    const size_t n = (size_t)2048 * 1024;
    for (size_t i = tid * 4; i < n; i += stride * 4) {
      float4 v = *(const float4*)(mk + i);
      ushort4 o;
      o.x = f2bf(v.x); o.y = f2bf(v.y); o.z = f2bf(v.z); o.w = f2bf(v.w);
      *(ushort4*)((unsigned short*)mkb + i) = o;
    }
  } else if (which == 3) {
    // mv [2048][1024] f32 -> mvT [1024][2048] bf16; tile = blockIdx.x of 32x64
    const int ti = blockIdx.x & 31;  // e-block (1024/32)
    const int tj = blockIdx.x >> 5;  // m-block (2048/32)
    const int tx = t & 31, ty = t >> 5;
#pragma unroll
    for (int r = 0; r < 4; ++r)
      tl[ty + r * 8][tx] = mv[(size_t)(tj * 32 + ty + r * 8) * 1024 + ti * 32 + tx];
    __syncthreads();
#pragma unroll
    for (int r = 0; r < 4; ++r)
      mvT[(size_t)(ti * 32 + ty + r * 8) * 2048 + tj * 32 + tx] =
          __float2bfloat16(tl[tx][ty + r * 8]);
  } else {
    const float isc = __uint_as_float(sc->max_x_bits) / 127.0f;
    const size_t n = (size_t)32768 * 1024;
    for (size_t i = tid * 4; i < n; i += stride * 4) {
      float4 v = *(const float4*)(x + i);
      char4 o;
      o.x = (char)(int)fminf(fmaxf(rintf(v.x / isc), -128.f), 127.f);
      o.y = (char)(int)fminf(fmaxf(rintf(v.y / isc), -128.f), 127.f);
      o.z = (char)(int)fminf(fmaxf(rintf(v.z / isc), -128.f), 127.f);
      o.w = (char)(int)fminf(fmaxf(rintf(v.w / isc), -128.f), 127.f);
      *(char4*)(qx8 + i) = o;
    }
  }
}

__global__ __launch_bounds__(256) void quant_act_i8_kernel(const float* __restrict__ x,
                                                           char* __restrict__ q,
                                                           const unsigned int* __restrict__ maxbits,
                                                           size_t n) {
  const float isc = __uint_as_float(*maxbits) / 127.0f;
  size_t tid = (size_t)blockIdx.x * blockDim.x + threadIdx.x;
  size_t stride = (size_t)gridDim.x * blockDim.x;
  for (size_t i = tid * 4; i < n; i += stride * 4) {
    float4 v = *(const float4*)(x + i);
    char4 o;
    o.x = (char)(int)fminf(fmaxf(rintf(v.x / isc), -128.f), 127.f);
    o.y = (char)(int)fminf(fmaxf(rintf(v.y / isc), -128.f), 127.f);
    o.z = (char)(int)fminf(fmaxf(rintf(v.z / isc), -128.f), 127.f);
    o.w = (char)(int)fminf(fmaxf(rintf(v.w / isc), -128.f), 127.f);
    *(char4*)(q + i) = o;
  }
}

// ---------------- softmax over rows of 2048, in-place bf16 ----------------
__global__ __launch_bounds__(256) void softmax_kernel(__hip_bfloat16* __restrict__ sims) {
  unsigned short* row = (unsigned short*)(sims + (size_t)blockIdx.x * 2048);
  const int t = threadIdx.x;
  const int l = t & 63, wv = t >> 6;
  uint4 r4 = *(const uint4*)(row + t * 8);
  float v[8];
  v[0] = __uint_as_float(r4.x << 16); v[1] = __uint_as_float(r4.x & 0xffff0000u);
  v[2] = __uint_as_float(r4.y << 16); v[3] = __uint_as_float(r4.y & 0xffff0000u);
  v[4] = __uint_as_float(r4.z << 16); v[5] = __uint_as_float(r4.z & 0xffff0000u);
  v[6] = __uint_as_float(r4.w << 16); v[7] = __uint_as_float(r4.w & 0xffff0000u);
  float m = v[0];
#pragma unroll
  for (int i = 1; i < 8; ++i) m = fmaxf(m, v[i]);
#pragma unroll
  for (int o = 32; o > 0; o >>= 1) m = fmaxf(m, __shfl_xor(m, o));
  __shared__ float red[4], red2[4];
  if (l == 0) red[wv] = m;
  __syncthreads();
  m = fmaxf(fmaxf(red[0], red[1]), fmaxf(red[2], red[3]));
  float s = 0.f;
#pragma unroll
  for (int i = 0; i < 8; ++i) { v[i] = expf(v[i] - m); s += v[i]; }
#pragma unroll
  for (int o = 32; o > 0; o >>= 1) s += __shfl_xor(s, o);
  if (l == 0) red2[wv] = s;
  __syncthreads();
  s = red2[0] + red2[1] + red2[2] + red2[3];
  unsigned short b[8];
#pragma unroll
  for (int i = 0; i < 8; ++i) b[i] = f2bf(v[i] / s);
  uint4 o4;
  o4.x = (unsigned)b[0] | ((unsigned)b[1] << 16);
  o4.y = (unsigned)b[2] | ((unsigned)b[3] << 16);
  o4.z = (unsigned)b[4] | ((unsigned)b[5] << 16);
  o4.w = (unsigned)b[6] | ((unsigned)b[7] << 16);
  *(uint4*)(row + t * 8) = o4;
}

// ------- unified 256x256 NT MFMA GEMM, 8-phase counted vmcnt, 32x32 MFMA -------
// C[m,n] = sum_k A[m,k]*B[n,k], 128-byte K-tiles (bf16 BK=64 / i8 BK=128).
// 512 threads = 8 waves (2M x 4N); per-wave output 128x64 = 4x2 32x32 frags.
// LDS [A0,A1,B0,B1][slot][16KiB]; 16B chunks XOR-swizzled: LDS chunk c holds
// global chunk c^(row&7) (pre-swizzled global_load_lds source; read applies
// chunk=(ks*2+hi)^(l&7)). Phases per tile: (mh,nh)=(0,0),(0,1),(1,0),(1,1),
// 8 MFMA each (2 row-frags x 4 K-steps). vmcnt(6) only at p4 (retires exactly
// the next K-tile's 8 loads); counted lgkm waits; schedule identical to the
// verified round-2 ledger.  EPI: 1=bf16(acc/32)  2=f32(acc+aux)+absmax
// 3=bf16(acc*sK+aux[col])  4=f32(acc*sO+aux[col]).
#define CFENCE() asm volatile("" ::: "memory")
#define BAR8() { CFENCE(); __builtin_amdgcn_s_barrier(); CFENCE(); }
#define WLGKM(N) { asm volatile("s_waitcnt lgkmcnt(" #N ")" ::: "memory"); __builtin_amdgcn_sched_barrier(0); }
#define WVM(N) asm volatile("s_waitcnt vmcnt(" #N ")" ::: "memory")

template <int EPI>
__global__ __launch_bounds__(512, 2) void gemm8(
    const char* __restrict__ A, const char* __restrict__ B, void* __restrict__ C,
    const float* __restrict__ aux, Scalars* __restrict__ sc,
    int Ndim, int KB, int nxShift) {
  constexpr bool I8 = (EPI >= 3);
  using FR  = typename std::conditional<I8, i32x4, bf16x8>::type;
  using ACC = typename std::conditional<I8, i32x16, f32x16>::type;
  __shared__ __align__(16) char lds[4][2][16384];  // [A0,A1,B0,B1][slot][16KiB]

  int bx, by;
  tile_swizzle(nxShift, bx, by);
  const int rowBlk = by * 256, colBlk = bx * 256;

  const int t = threadIdx.x, w = t >> 6, l = t & 63;
  const int wm = w >> 2, wn = w & 3;
  const int l31 = l & 31, hi = l >> 5;
  const int NT = KB >> 7, NIT = NT >> 1;

  // per-thread staging byte-offsets (K-invariant; add tk*128)
  int voA[2][2], voB[2][2];
#pragma unroll
  for (int hf = 0; hf < 2; ++hf)
#pragma unroll
    for (int j = 0; j < 2; ++j) {
      const int idx = j * 64 + (t >> 3);
      const int kby = ((t & 7) ^ (idx & 7)) << 4;
      voA[hf][j] = (rowBlk + ((idx >> 6) << 7) + (hf << 6) + (idx & 63)) * KB + kby;
      voB[hf][j] = (colBlk + ((idx >> 5) << 6) + (hf << 5) + (idx & 31)) * KB + kby;
    }

  // fragment-read bases; swizzled k-chunk offsets per K-step
  int ofsK[4];
#pragma unroll
  for (int ks = 0; ks < 4; ++ks)
    ofsK[ks] = ((((ks ^ ((l >> 1) & 3)) << 1) | (hi ^ (l & 1))) << 4);
  const char* bA = &lds[0][0][0] + (wm * 64 + l31) * 128;
  const char* bB = &lds[2][0][0] + (wn * 32 + l31) * 128;

#define STG_A(slot, hf, tk)                                                         \
  if ((tk) < NT) {                                                                  \
    _Pragma("unroll") for (int j = 0; j < 2; ++j)                                   \
      async16(&lds[hf][slot][j * 8192 + (w << 10)],                                 \
              A + (((size_t)(tk)) << 7) + voA[hf][j]);                              \
  }
#define STG_B(slot, hf, tk)                                                         \
  if ((tk) < NT) {                                                                  \
    _Pragma("unroll") for (int j = 0; j < 2; ++j)                                   \
      async16(&lds[2 + (hf)][slot][j * 8192 + (w << 10)],                           \
              B + (((size_t)(tk)) << 7) + voB[hf][j]);                              \
  }

#define LD_A(dst, slot, hf, f01, ks) \
  dst = *(const FR*)(bA + ((hf) * 32768 + (slot) * 16384 + (f01) * 4096) + ofsK[ks]);
#define LD_B(dst, slot, nh, ks) \
  dst = *(const FR*)(bB + ((nh) * 32768 + (slot) * 16384) + ofsK[ks]);

#define R_A0(s) { _Pragma("unroll") for (int f_ = 0; f_ < 2; ++f_) _Pragma("unroll") for (int k_ = 0; k_ < 4; ++k_) LD_A(af[f_][k_], s, 0, f_, k_); }
#define R_A1(s) { _Pragma("unroll") for (int f_ = 0; f_ < 2; ++f_) _Pragma("unroll") for (int k_ = 0; k_ < 4; ++k_) LD_A(af[f_][k_], s, 1, f_, k_); }
#define R_B0(s) { _Pragma("unroll") for (int k_ = 0; k_ < 4; ++k_) LD_B(b0[k_], s, 0, k_); }
#define R_B1(s) { _Pragma("unroll") for (int k_ = 0; k_ < 4; ++k_) LD_B(b1[k_], s, 1, k_); }

#define MM32(MH, NH, BR)                                                            \
  __builtin_amdgcn_s_setprio(1);                                                    \
  _Pragma("unroll") for (int k_ = 0; k_ < 4; ++k_)                                  \
    _Pragma("unroll") for (int f_ = 0; f_ < 2; ++f_)                                \
      acc[(MH) * 2 + f_][NH] = mm32(af[f_][k_], BR[k_], acc[(MH) * 2 + f_][NH]);    \
  __builtin_amdgcn_s_setprio(0);

// Per-tile 4-phase step (round-2 ledger). Entering p1: A0(8)+B0(4) in flight.
#define TSTEP(s, tk, last)                                                          \
  {                                                                                 \
    /* p1: (mh0,nh0). issue B1 reads for p2; wait retires A0+B0. */                 \
    R_B1(s);                                                                        \
    STG_A((s) ^ 1, 1, (tk) + 1);                                                    \
    BAR8(); WLGKM(4);                                                               \
    MM32(0, 0, b0);                                                                 \
    BAR8();                                                                         \
    /* p2: (mh0,nh1). A1 reads issue AFTER the MFMAs (WAR on af by dataflow). */    \
    STG_A(s, 0, (tk) + 2);                                                          \
    BAR8(); WLGKM(0);                                                               \
    MM32(0, 1, b1);                                                                 \
    R_A1(s);                                                                        \
    BAR8();                                                                         \
    /* p3: (mh1,nh0). */                                                            \
    STG_B(s, 0, (tk) + 2);                                                          \
    BAR8(); WLGKM(0);                                                               \
    MM32(1, 0, b0);                                                                 \
    BAR8();                                                                         \
    /* p4: (mh1,nh1). vmcnt(6) retires next tile; then prefetch its A0+B0. */       \
    STG_B(s, 1, (tk) + 2);                                                          \
    if (last) { WVM(0); } else { WVM(6); }                                          \
    BAR8();                                                                         \
    MM32(1, 1, b1);                                                                 \
    R_A0((s) ^ 1); R_B0((s) ^ 1);                                                   \
  }

  FR af[2][4], b0[4], b1[4];
  ACC acc[4][2] = {};

  // Prologue: tile0 (A0,B0,B1,A1) + tile1 (A0,B0,B1); WVM(6) retires exactly
  // tile0's 8 loads; then tile0's A0+B0 fragments are read.
  STG_A(0, 0, 0); STG_B(0, 0, 0); STG_B(0, 1, 0); STG_A(0, 1, 0);
  CFENCE();
  STG_A(1, 0, 1); STG_B(1, 0, 1); STG_B(1, 1, 1);
  WVM(6);
  BAR8();
  R_A0(0); R_B0(0);

  for (int it = 0; it < NIT; ++it) {
    const bool last = (it == NIT - 1);
    TSTEP(0, it * 2, last);
    TSTEP(1, it * 2 + 1, last);
  }

  // ---------------- epilogue ----------------
  float sK = 0.0f;
  if constexpr (EPI == 3)
    sK = (float)(sc->sum_wk * (1.0 / 1048576.0)) * (__uint_as_float(sc->max_x_bits) / 127.0f);
  if constexpr (EPI == 4)
    sK = (float)(sc->sum_wo * (1.0 / 1048576.0)) * (__uint_as_float(sc->max_y_bits) / 127.0f);

  float amax = 0.0f;
#pragma unroll
  for (int f = 0; f < 4; ++f) {
#pragma unroll
    for (int g = 0; g < 2; ++g) {
      const int col = colBlk + wn * 64 + g * 32 + l31;
#pragma unroll
      for (int r = 0; r < 16; ++r) {
        const int row = rowBlk + wm * 128 + f * 32 + (r & 3) + 8 * (r >> 2) + 4 * hi;
        if constexpr (EPI == 1) {
          ((__hip_bfloat16*)C)[(size_t)row * Ndim + col] =
              __float2bfloat16(acc[f][g][r] * 0.03125f);
        } else if constexpr (EPI == 2) {
          float v = acc[f][g][r] + aux[(size_t)row * Ndim + col];
          ((float*)C)[(size_t)row * Ndim + col] = v;
          amax = fmaxf(amax, fabsf(v));
        } else if constexpr (EPI == 3) {
          ((__hip_bfloat16*)C)[(size_t)row * Ndim + col] =
              __float2bfloat16((float)acc[f][g][r] * sK + aux[col]);
        } else {
          ((float*)C)[(size_t)row * Ndim + col] = (float)acc[f][g][r] * sK + aux[col];
        }
      }
    }
  }

  if constexpr (EPI == 2) {
    __shared__ float wred[8];
#pragma unroll
    for (int o = 32; o > 0; o >>= 1) amax = fmaxf(amax, __shfl_xor(amax, o));
    if (l == 0) wred[w] = amax;
    __syncthreads();
    if (t == 0) {
      float m = wred[0];
#pragma unroll
      for (int i = 1; i < 8; ++i) m = fmaxf(m, wred[i]);
      atomicMax(&sc->max_y_bits, __float_as_uint(m));
    }
  }
#undef STG_A
#undef STG_B
#undef LD_A
#undef LD_B
#undef R_A0
#undef R_A1
#undef R_B0
#undef R_B1
#undef MM32
#undef TSTEP
}

extern "C" void kernel_launch(void* const* d_in, const int* in_sizes, int n_in,
                              void* d_out, int out_size, void* d_ws, size_t ws_size,
                              hipStream_t stream) {
  (void)in_sizes; (void)n_in; (void)out_size; (void)ws_size;
  const float* x  = (const float*)d_in[0];   // [8,4096,1024]
  const float* mk = (const float*)d_in[1];   // [2048,1024]
  const float* mv = (const float*)d_in[2];   // [2048,1024]
  const float* Wk = (const float*)d_in[3];   // [1024,1024]
  const float* bk = (const float*)d_in[4];   // [1024]
  // d_in[5], d_in[6] = Wv, bv -> dead w.r.t. output; skipped.
  const float* Wo = (const float*)d_in[7];
  const float* bo = (const float*)d_in[8];
  float* out = (float*)d_out;

  const int M = 32768, E = 1024, MEM = 2048;

  char* ws = (char*)d_ws;
  Scalars* sc = (Scalars*)ws;
  const size_t off0 = 256;
  char* qx8 = ws + off0;                                            // 32 MB
  __hip_bfloat16* qk = (__hip_bfloat16*)(ws + off0 + (size_t)M * E); // 64 MB
  float* y = (float*)(ws + off0);                                   // reuses qx8+qk region (128 MB)
  const size_t off1 = off0 + (size_t)M * E * 4;
  __hip_bfloat16* sims = (__hip_bfloat16*)(ws + off1);              // 128 MB
  char* qy8 = (char*)sims;                                          // reuses sims (32 MB)
  const size_t off2 = off1 + (size_t)M * MEM * 2;
  char* qWk8 = ws + off2;                                           // 1 MB
  char* qWo8 = qWk8 + (size_t)E * E;                                // 1 MB
  __hip_bfloat16* mkb = (__hip_bfloat16*)(qWo8 + (size_t)E * E);    // 4 MB
  __hip_bfloat16* mvT = mkb + (size_t)MEM * E;                      // 4 MB

  hipMemsetAsync(ws, 0, 256, stream);

  // stats: abssum(Wk), abssum(Wo), absmax(x) in one launch
  stats_kernel<<<dim3(1024, 3), dim3(256), 0, stream>>>(Wk, Wo, x, sc);
  // prep: quantW(Wk), quantW(Wo), cast(mk), transpose(mv), quantAct(x)
  prep_kernel<<<dim3(2048, 5), dim3(256), 0, stream>>>(Wk, Wo, mk, mv, x, qWk8, qWo8,
                                                       mkb, mvT, qx8, sc);

  // qk = bf16((qx @ qWk^T) * s_k + bk)      [i8, KB=1024]
  gemm8<3><<<dim3((E / 256) * (M / 256)), dim3(512), 0, stream>>>(
      qx8, qWk8, qk, bk, sc, E, E, 2);
  // sims = bf16((qk @ mk^T) / 32)           [bf16, KB=2048]
  gemm8<1><<<dim3((MEM / 256) * (M / 256)), dim3(512), 0, stream>>>(
      (const char*)qk, (const char*)mkb, sims, nullptr, sc, MEM, 2 * E, 3);
  // softmax rows (in place)
  softmax_kernel<<<dim3(M), dim3(256), 0, stream>>>(sims);
  // y = probs @ mv + x   (+ global max|y|)   [bf16, KB=4096]
  gemm8<2><<<dim3((E / 256) * (M / 256)), dim3(512), 0, stream>>>(
      (const char*)sims, (const char*)mvT, y, x, sc, E, 2 * MEM, 2);
  // qy = quant(y)
  quant_act_i8_kernel<<<dim3(2048), dim3(256), 0, stream>>>(y, qy8, &sc->max_y_bits, (size_t)M * E);
  // out = (qy @ qWo^T) * s_o + bo           [i8, KB=1024]
  gemm8<4><<<dim3((E / 256) * (M / 256)), dim3(512), 0, stream>>>(
      qy8, qWo8, out, bo, sc, E, E, 2);
}